// Round 1
// 544.578 us; speedup vs baseline: 1.2879x; 1.2879x over previous
//
#include <hip/hip_runtime.h>
#include <math.h>

#define AN 120000
#define NB 8
#define NC 80
#define TOPN 1000
#define MAXDET 100
#define CAND_CAP 2048
#define CAND_T 0.99985f

typedef unsigned long long u64;
typedef unsigned int u32;

// identity pass-through that blocks FMA contraction / reassociation across it
__device__ __forceinline__ float opaquef(float x) { asm volatile("" : "+v"(x)); return x; }

// ---------------------------------------------------------------------------
// Phase A: per-anchor max/argmax over 80 classes -> unique 48-bit sort key.
// key = (float_bits(score) << 17) | (131071 - anchor)   (score >= 0 -> bits monotonic)
// Coalesced: stage 32-anchor tiles (32x80 f32) through LDS with stride-81 padding.
// NEW: anchors with score >= CAND_T also append their key to a per-image
// candidate buffer (expected ~1430/image; top-1000 cutoff is ~0.99990 for
// max-of-80-uniform scores, so candidates are a superset of the top-1000
// whenever cnt >= 1000 -- select_kernel verifies and falls back otherwise).
// ---------------------------------------------------------------------------
__global__ __launch_bounds__(256) void score_kernel(const float* __restrict__ cls,
                                                    u64* __restrict__ keys,
                                                    int* __restrict__ cls_out,
                                                    u64* __restrict__ cand,
                                                    u32* __restrict__ cand_cnt) {
    __shared__ float buf[4][32 * 81];
    const int tid = threadIdx.x;
    const int wave = tid >> 6, lane = tid & 63;
    const long long blockbase = (long long)blockIdx.x * 256;

    for (int h = 0; h < 2; ++h) {
        const long long abase = blockbase + wave * 64 + h * 32;  // first anchor of half-tile
        const float4* src = (const float4*)(cls + abase * NC);
        float* Bf = buf[wave];
#pragma unroll
        for (int it = 0; it < 10; ++it) {
            int f = lane + it * 64;           // float4 index within 32x80 tile (0..639)
            float4 v = src[f];                // fully coalesced
            int anch = f / 20, pos = (f % 20) * 4;
            float* dst = Bf + anch * 81 + pos;
            dst[0] = v.x; dst[1] = v.y; dst[2] = v.z; dst[3] = v.w;
        }
        __syncthreads();
        // 2 lanes per anchor, 40 elems each (stride-81 rows -> conflict-free b32 reads)
        int anch = lane >> 1, half = lane & 1;
        const float* row = Bf + anch * 81 + half * 40;
        float best = -1.0f; int bi = 0;
#pragma unroll
        for (int i = 0; i < 40; ++i) {
            float v = row[i];
            if (v > best) { best = v; bi = i; }   // strict > keeps first occurrence
        }
        bi += half * 40;
        float ov = __shfl_xor(best, 1);
        int   oi = __shfl_xor(bi, 1);
        if (ov > best || (ov == best && oi < bi)) { best = ov; bi = oi; }
        if (half == 0) {
            long long aglob = abase + anch;
            int a = (int)(aglob % AN);
            u64 key = ((u64)__float_as_uint(best) << 17) | (u64)(131071 - a);
            keys[aglob]    = key;
            cls_out[aglob] = bi;
            if (best >= CAND_T) {
                int im = (int)(aglob / AN);
                u32 p = atomicAdd(&cand_cnt[im], 1u);
                if (p < CAND_CAP) cand[(size_t)im * CAND_CAP + p] = key;
            }
        }
        __syncthreads();
    }
}

// ---------------------------------------------------------------------------
// Phase B: exact top-1000 per image.
// FAST PATH (taken when 1000 <= cand_cnt <= 2048, i.e. always for this data):
//   bitonic-sort the <=2048 pre-filtered candidates in LDS -- no passes over
//   the 960K-key array at all.
// FALLBACK (exact for any input): original 6-level 8-bit radix select on the
//   unique 48-bit keys, then collect + bitonic sort. One block per image.
// ---------------------------------------------------------------------------
__global__ __launch_bounds__(1024) void select_kernel(const u64* __restrict__ keys,
                                                      const u64* __restrict__ cand,
                                                      const u32* __restrict__ cand_cnt,
                                                      u64* __restrict__ topk) {
    const int img = blockIdx.x;
    const int tid = threadIdx.x;

    __shared__ u64 stopk[CAND_CAP];
    __shared__ u32 hist[256];
    __shared__ u32 sscan[256];
    __shared__ u32 s_need, s_digit, s_cnt;
    __shared__ u64 s_prefix;

    const u32 cnt = cand_cnt[img];
    if (cnt >= (u32)TOPN && cnt <= (u32)CAND_CAP) {
        // ---- fast path: sort the candidate superset ----
        const u64* c = cand + (size_t)img * CAND_CAP;
        for (int i = tid; i < CAND_CAP; i += 1024)
            stopk[i] = (i < (int)cnt) ? ~c[i] : ~0ull;   // invert -> ascending = K desc
        __syncthreads();
        for (int kk = 2; kk <= CAND_CAP; kk <<= 1) {
            for (int j = kk >> 1; j > 0; j >>= 1) {
                for (int i = tid; i < CAND_CAP; i += 1024) {
                    int ixj = i ^ j;
                    if (ixj > i) {
                        u64 a = stopk[i], b = stopk[ixj];
                        bool asc = ((i & kk) == 0);
                        if ((a > b) == asc) { stopk[i] = b; stopk[ixj] = a; }
                    }
                }
                __syncthreads();
            }
        }
        topk[img * 1024 + tid] = ~stopk[tid];
        return;
    }

    // ---- fallback: exact radix select over all AN keys ----
    const u64* k = keys + (size_t)img * AN;

    if (tid == 0) { s_need = TOPN; s_prefix = 0; s_cnt = 0; }
    if (tid < 1024) stopk[tid] = ~0ull;   // inverted-key pad (sorts last)
    __syncthreads();

    for (int lvl = 0; lvl < 6; ++lvl) {
        const int shift = 40 - 8 * lvl;
        if (tid < 256) hist[tid] = 0;
        __syncthreads();
        const u64 P = s_prefix;
        const u32 need = s_need;
        for (int i = tid; i < AN; i += 1024) {
            u64 K = k[i];
            if ((K >> (shift + 8)) == P)
                atomicAdd(&hist[(u32)((K >> shift) & 255)], 1u);
        }
        __syncthreads();
        if (tid < 256) sscan[tid] = hist[tid];
        __syncthreads();
        // suffix sum over 256 bins (Hillis-Steele)
        for (int off = 1; off < 256; off <<= 1) {
            u32 v = 0;
            if (tid < 256 && tid + off < 256) v = sscan[tid + off];
            __syncthreads();
            if (tid < 256) sscan[tid] += v;
            __syncthreads();
        }
        if (tid < 256) {
            u32 above = (tid == 255) ? 0u : sscan[tid + 1];
            if (sscan[tid] >= need && above < need) {   // unique d (sscan non-increasing)
                s_digit = (u32)tid;
                s_need = need - above;
            }
        }
        __syncthreads();
        if (tid == 0) s_prefix = (s_prefix << 8) | (u64)s_digit;
        __syncthreads();
    }

    const u64 T = s_prefix;   // exact key of the 1000th-largest (keys unique)
    for (int i = tid; i < AN; i += 1024) {
        u64 K = k[i];
        if (K >= T) {
            u32 pos = atomicAdd(&s_cnt, 1u);
            if (pos < 1024) stopk[pos] = ~K;   // invert -> ascending sort = K descending
        }
    }
    __syncthreads();

    // bitonic ascending sort of inverted keys, n = 1024
    for (int kk = 2; kk <= 1024; kk <<= 1) {
        for (int j = kk >> 1; j > 0; j >>= 1) {
            int ixj = tid ^ j;
            if (ixj > tid) {
                u64 a = stopk[tid], b = stopk[ixj];
                bool asc = ((tid & kk) == 0);
                if ((a > b) == asc) { stopk[tid] = b; stopk[ixj] = a; }
            }
            __syncthreads();
        }
    }
    topk[img * 1024 + tid] = ~stopk[tid];
}

// ---------------------------------------------------------------------------
// Phase C: decode the 8x1000 selected boxes (exact reference arithmetic).
// ---------------------------------------------------------------------------
__global__ __launch_bounds__(256) void decode_kernel(const u64* __restrict__ topk,
                                                     const int* __restrict__ clsin,
                                                     const float* __restrict__ reg,
                                                     const float* __restrict__ anch,
                                                     float* __restrict__ tsc,
                                                     int* __restrict__ tcl,
                                                     float* __restrict__ tbox) {
    int t = blockIdx.x * 256 + threadIdx.x;
    if (t >= NB * 1024) return;
    int img = t >> 10, j = t & 1023;
    if (j >= TOPN) return;

    u64 K = topk[t];
    u32 sb = (u32)(K >> 17);
    int idx = 131071 - (int)(K & 0x1FFFF);
    float score = __uint_as_float(sb);
    size_t gi = (size_t)img * AN + idx;

    float4 r = ((const float4*)reg)[gi];
    float4 a = ((const float4*)anch)[gi];

    float aw = a.z - a.x, ah = a.w - a.y;
    float acx = a.x + 0.5f * aw, acy = a.y + 0.5f * ah;   // 0.5*x exact -> FMA-safe
    float rx = opaquef(r.x * 0.1f), ry = opaquef(r.y * 0.1f);
    float rw = opaquef(r.z * 0.2f), rh = opaquef(r.w * 0.2f);
    float pw = opaquef((float)exp((double)rw) * aw);      // ~correctly-rounded f32 exp
    float ph = opaquef((float)exp((double)rh) * ah);
    float pcx = opaquef(rx * aw) + acx;
    float pcy = opaquef(ry * ah) + acy;
    float x1 = truncf(pcx - 0.5f * pw);
    float y1 = truncf(pcy - 0.5f * ph);
    float x2 = truncf(pcx + 0.5f * pw);
    float y2 = truncf(pcy + 0.5f * ph);
    x1 = fmaxf(x1, 0.0f); y1 = fmaxf(y1, 0.0f);
    x2 = fminf(x2, 639.0f); y2 = fminf(y2, 639.0f);

    tsc[t] = score;
    tcl[t] = clsin[gi];
    ((float4*)tbox)[t] = make_float4(x1, y1, x2, y2);
}

// ---------------------------------------------------------------------------
// Phase D: NMS suppression bitmask. One wave per row i; 16 x 64-bit words of
// (iou > 0.5 && j > i). Boxes are small integers -> IoU math is exact.
// ---------------------------------------------------------------------------
__global__ __launch_bounds__(256) void mask_kernel(const float* __restrict__ tbox,
                                                   u64* __restrict__ masks) {
    __shared__ float4 sb[1000];
    __shared__ float  sarea[1000];
    const int img = blockIdx.x / 250;
    const int grp = blockIdx.x % 250;
    const int tid = threadIdx.x;

    for (int t = tid; t < 1000; t += 256) {
        float4 b = ((const float4*)tbox)[img * 1024 + t];
        sb[t] = b;
        sarea[t] = (b.z - b.x) * (b.w - b.y);
    }
    __syncthreads();

    const int wave = tid >> 6, lane = tid & 63;
    const int i = grp * 4 + wave;            // 0..999
    float4 bi = sb[i];
    float  ai = sarea[i];
#pragma unroll
    for (int w = 0; w < 16; ++w) {
        int j = w * 64 + lane;
        bool p = false;
        if (j < 1000 && j > i) {
            float4 bj = sb[j];
            float ltx = fmaxf(bi.x, bj.x), lty = fmaxf(bi.y, bj.y);
            float rbx = fminf(bi.z, bj.z), rby = fminf(bi.w, bj.w);
            float dx = fmaxf(rbx - ltx, 0.0f), dy = fmaxf(rby - lty, 0.0f);
            float inter = dx * dy;                       // exact int
            float uni = ai + sarea[j] - inter;           // exact int
            p = (inter / uni) > 0.5f;                    // IEEE div, bit-exact vs numpy
        }
        u64 m = __ballot(p);
        if (lane == 0) masks[((size_t)img * 1000 + i) * 16 + w] = m;
    }
}

// ---------------------------------------------------------------------------
// Phase E: sequential greedy scan (one wave per image, lane l owns mask word l),
// early-exit at 100 keepers, then write the packed outputs.
// NEW: the 1000 scores are preloaded into LDS so the serial loop's critical
// path is shuffle + LDS read instead of a dependent global load per iteration.
// ---------------------------------------------------------------------------
__global__ __launch_bounds__(64) void scan_kernel(const u64* __restrict__ masks,
                                                  const float* __restrict__ tsc,
                                                  const int* __restrict__ tcl,
                                                  const float* __restrict__ tbox,
                                                  float* __restrict__ out) {
    const int img = blockIdx.x;
    const int lane = threadIdx.x;
    __shared__ int keeplist[MAXDET];
    __shared__ float ssc[TOPN];

    for (int i = lane; i < TOPN; i += 64) ssc[i] = tsc[img * 1024 + i];
    __syncthreads();

    u64 remv = 0;
    int kept = 0;
    for (int i = 0; i < TOPN; ++i) {
        int word = i >> 6, bit = i & 63;
        u64 rw = __shfl(remv, word);
        bool removed = (rw >> bit) & 1ull;
        float sc = ssc[i];
        if (sc > 0.05f && !removed) {
            if (lane == 0) keeplist[kept] = i;
            kept++;
            if (kept >= MAXDET) break;        // first 100 keepers fully determine output
            if (lane < 16) remv |= masks[((size_t)img * 1000 + i) * 16 + lane];
        }
    }
    __syncthreads();

    const int n_keep = kept;
    for (int s = lane; s < MAXDET; s += 64) {
        int o = img * MAXDET + s;
        if (s < n_keep) {
            int i = keeplist[s];
            out[o] = ssc[i];
            out[NB * MAXDET + o] = (float)tcl[img * 1024 + i];
            ((float4*)(out + 2 * NB * MAXDET))[o] = ((const float4*)tbox)[img * 1024 + i];
        } else {
            out[o] = -1.0f;
            out[NB * MAXDET + o] = -1.0f;
            ((float4*)(out + 2 * NB * MAXDET))[o] = make_float4(-1.0f, -1.0f, -1.0f, -1.0f);
        }
    }
}

// ---------------------------------------------------------------------------
extern "C" void kernel_launch(void* const* d_in, const int* in_sizes, int n_in,
                              void* d_out, int out_size, void* d_ws, size_t ws_size,
                              hipStream_t stream) {
    const float* cls  = (const float*)d_in[0];
    const float* reg  = (const float*)d_in[1];
    const float* anch = (const float*)d_in[2];
    float* out = (float*)d_out;

    // workspace layout (u64-first for alignment), ~13.0 MB total
    u64* keys   = (u64*)d_ws;                       // NB*AN
    u64* topk   = keys + (size_t)NB * AN;           // NB*1024
    u64* masks  = topk + NB * 1024;                 // NB*1000*16
    u64* cand   = masks + (size_t)NB * 1000 * 16;   // NB*CAND_CAP
    int* clsmax = (int*)(cand + (size_t)NB * CAND_CAP);     // NB*AN
    float* tbox = (float*)(clsmax + (size_t)NB * AN);       // NB*1024*4
    float* tsc  = tbox + NB * 1024 * 4;             // NB*1024
    int*   tcl  = (int*)(tsc + NB * 1024);          // NB*1024
    u32*   ccnt = (u32*)(tcl + NB * 1024);          // NB

    hipMemsetAsync(ccnt, 0, NB * sizeof(u32), stream);
    hipLaunchKernelGGL(score_kernel,  dim3(3750), dim3(256),  0, stream, cls, keys, clsmax, cand, ccnt);
    hipLaunchKernelGGL(select_kernel, dim3(NB),   dim3(1024), 0, stream, keys, cand, ccnt, topk);
    hipLaunchKernelGGL(decode_kernel, dim3(32),   dim3(256),  0, stream, topk, clsmax, reg, anch, tsc, tcl, tbox);
    hipLaunchKernelGGL(mask_kernel,   dim3(2000), dim3(256),  0, stream, tbox, masks);
    hipLaunchKernelGGL(scan_kernel,   dim3(NB),   dim3(64),   0, stream, masks, tsc, tcl, tbox, out);
}